// Round 7
// baseline (345.256 us; speedup 1.0000x reference)
//
#include <hip/hip_runtime.h>

// Focal loss (gamma=2, w0=w1=1) mean over N=2^25: -mean(log(s)*(1-s)^2),
// s = t ? p : 1-p. SINGLE fused kernel: grid-stride all-nt streaming +
// last-block-done final reduction (no second launch).
//
// R9 post-mortem: all-nt -10.8us e2e (250.8). Partial ~75us => ~3.6 TB/s
// pure-read -- already above every documented read-side rate on this chip
// (copy 6.29 = 3.15R+3.15W, RMSNorm 4.89 ~ 2.45R); BW has been pattern/
// MLP/cache-policy insensitive across six structures. Remaining structural
// waste: second kernel + launch gap + 1-block GPU-idle tail (~8-15us).
// R10: fuse via last-block-done. Device-global counter (load-time zero,
// SELF-RESETTING via atomicExch(0) by last block -> iteration-safe, no
// memset). Cross-XCD per G16: store partials -> __threadfence (agent
// fence = L2 wb) -> device-scope atomicAdd; last block: fence (inv) ->
// read partials. Final sum replicates old focal_final order exactly
// (stride-256 + same shuffle tree) so absmax stays 0.
// Predict: e2e 235-244us. ~250 => launch was free, BW only lever left.
// FAIL => fence insufficient, revert to R9 two-kernel.

typedef float v4f __attribute__((ext_vector_type(4)));
typedef int   v4i __attribute__((ext_vector_type(4)));

constexpr int   N_TOTAL   = 33554432;
constexpr int   N_VEC     = N_TOTAL / 4;          // 8388608 float4
constexpr int   THREADS   = 256;
constexpr int   BLOCKS    = 2048;
constexpr int   GTHREADS  = BLOCKS * THREADS;     // 524288
constexpr int   STEPS     = N_VEC / GTHREADS;     // 16
constexpr float NEG_INV_N = -1.0f / 33554432.0f;

__device__ int g_counter = 0;   // module-load zeroed; self-resetting below

__device__ __forceinline__ float term4(v4f p, v4i t) {
    float r = 0.0f;
#pragma unroll
    for (int j = 0; j < 4; ++j) {
        float s = (t[j] == 1) ? p[j] : (1.0f - p[j]);
        float q = 1.0f - s;
        r += __logf(s) * q * q;
    }
    return r;
}

__global__ __launch_bounds__(THREADS) void focal_fused_kernel(
    const v4f* __restrict__ inp,
    const v4i* __restrict__ tgt,
    float* __restrict__ partials,
    float* __restrict__ out)
{
    const int gtid = blockIdx.x * THREADS + threadIdx.x;

    float acc = 0.0f;
#pragma unroll
    for (int k = 0; k < STEPS; ++k) {
        const int idx = gtid + k * GTHREADS;            // coherent sweep
        v4f p = __builtin_nontemporal_load(&inp[idx]);  // nt: no L3 churn
        v4i t = __builtin_nontemporal_load(&tgt[idx]);
        acc += term4(p, t);
    }

    // wave-64 shuffle reduction
#pragma unroll
    for (int off = 32; off > 0; off >>= 1)
        acc += __shfl_down(acc, off, 64);

    __shared__ float ws[THREADS / 64];
    const int lane = threadIdx.x & 63;
    const int wave = threadIdx.x >> 6;
    if (lane == 0) ws[wave] = acc;
    __syncthreads();

    // ---- last-block-done fused final reduction ----
    __shared__ bool is_last;
    if (threadIdx.x == 0) {
        partials[blockIdx.x] = ws[0] + ws[1] + ws[2] + ws[3];
        __threadfence();                       // agent fence: L2 writeback
        int done = atomicAdd(&g_counter, 1);   // device-scope by default
        is_last = (done == BLOCKS - 1);
    }
    __syncthreads();

    if (is_last) {
        __threadfence();                       // acquire: invalidate stale
        float facc = 0.0f;
#pragma unroll
        for (int k = 0; k < BLOCKS / THREADS; ++k)
            facc += partials[k * THREADS + threadIdx.x];

#pragma unroll
        for (int off = 32; off > 0; off >>= 1)
            facc += __shfl_down(facc, off, 64);

        if (lane == 0) ws[wave] = facc;
        __syncthreads();

        if (threadIdx.x == 0) {
            out[0] = (ws[0] + ws[1] + ws[2] + ws[3]) * NEG_INV_N;
            atomicExch(&g_counter, 0);         // self-reset for next iter
        }
    }
}

extern "C" void kernel_launch(void* const* d_in, const int* in_sizes, int n_in,
                              void* d_out, int out_size, void* d_ws, size_t ws_size,
                              hipStream_t stream) {
    const v4f* inp = (const v4f*)d_in[0];
    const v4i* tgt = (const v4i*)d_in[1];
    float*     out = (float*)d_out;
    float*     partials = (float*)d_ws;   // 8 KB scratch

    focal_fused_kernel<<<BLOCKS, THREADS, 0, stream>>>(inp, tgt, partials, out);
}

// Round 8
// 261.776 us; speedup vs baseline: 1.3189x; 1.3189x over previous
//
#include <hip/hip_runtime.h>

// Focal loss (gamma=2, w0=w1=1) mean over N=2^25: -mean(log(s)*(1-s)^2),
// s = t ? p : 1-p. SINGLE fused kernel: grid-stride all-nt streaming +
// last-block-done final reduction.
//
// R10 post-mortem: fusion v1 regressed (kernel 75 -> 144.7us) and the
// profile shows WHY: hbm_gbps fell to 929 at unchanged occupancy.
// __threadfence() = seq-cst agent fence = cache-WIDE buffer_wbl2/inv on
// gfx950; 2048 of them thrashed the L2s under the concurrently-running
// blocks' nt-read pipeline. Fusion idea fine; fence granularity wrong.
// R11 fusion v2: zero cache-wide maintenance ops. All cross-block comm
// via L2-BYPASSING relaxed atomics (LLVM AMDGPU model: relaxed atomics
// emit only sc0/sc1 bypass bits, no wbl2/inv):
//   writer: atomic_store(partials, RELAXED, AGENT) -> s_waitcnt vmcnt(0)
//           (store at coherence point) -> atomic_fetch_add(ctr, RELAXED).
//   last:   atomic_load(partials, RELAXED, AGENT) x8/thread (bypass reads
//           -> no stale L2, no invalidate needed).
// Sum order identical to old final kernel (stride-256 + same shuffle
// tree) -> absmax 0. Counter self-resets -> iteration-safe.
// Predict: kernel ~76-80us, e2e 238-246, hbm_gbps ~1300. e2e >255 =>
// revert to R9 two-kernel and declare roofline (~250.8; pure-read
// ~3.6 TB/s insensitive across 7 structures).

typedef float v4f __attribute__((ext_vector_type(4)));
typedef int   v4i __attribute__((ext_vector_type(4)));

constexpr int   N_TOTAL   = 33554432;
constexpr int   N_VEC     = N_TOTAL / 4;          // 8388608 float4
constexpr int   THREADS   = 256;
constexpr int   BLOCKS    = 2048;
constexpr int   GTHREADS  = BLOCKS * THREADS;     // 524288
constexpr int   STEPS     = N_VEC / GTHREADS;     // 16
constexpr float NEG_INV_N = -1.0f / 33554432.0f;

__device__ int g_counter = 0;   // module-load zeroed; self-resetting below

__device__ __forceinline__ float term4(v4f p, v4i t) {
    float r = 0.0f;
#pragma unroll
    for (int j = 0; j < 4; ++j) {
        float s = (t[j] == 1) ? p[j] : (1.0f - p[j]);
        float q = 1.0f - s;
        r += __logf(s) * q * q;
    }
    return r;
}

__global__ __launch_bounds__(THREADS) void focal_fused_kernel(
    const v4f* __restrict__ inp,
    const v4i* __restrict__ tgt,
    float* __restrict__ partials,
    float* __restrict__ out)
{
    const int gtid = blockIdx.x * THREADS + threadIdx.x;

    float acc = 0.0f;
#pragma unroll
    for (int k = 0; k < STEPS; ++k) {
        const int idx = gtid + k * GTHREADS;            // coherent sweep
        v4f p = __builtin_nontemporal_load(&inp[idx]);  // nt: no L3 churn
        v4i t = __builtin_nontemporal_load(&tgt[idx]);
        acc += term4(p, t);
    }

    // wave-64 shuffle reduction
#pragma unroll
    for (int off = 32; off > 0; off >>= 1)
        acc += __shfl_down(acc, off, 64);

    __shared__ float ws[THREADS / 64];
    const int lane = threadIdx.x & 63;
    const int wave = threadIdx.x >> 6;
    if (lane == 0) ws[wave] = acc;
    __syncthreads();

    // ---- last-block-done fused final reduction (no cache-wide ops) ----
    __shared__ bool is_last;
    if (threadIdx.x == 0) {
        const float bsum = ws[0] + ws[1] + ws[2] + ws[3];
        // write-through store to the coherence point (sc0/sc1, per-line)
        __hip_atomic_store(&partials[blockIdx.x], bsum,
                           __ATOMIC_RELAXED, __HIP_MEMORY_SCOPE_AGENT);
        // make it globally visible before announcing completion
        asm volatile("s_waitcnt vmcnt(0)" ::: "memory");
        const int done = __hip_atomic_fetch_add(&g_counter, 1,
                           __ATOMIC_RELAXED, __HIP_MEMORY_SCOPE_AGENT);
        is_last = (done == BLOCKS - 1);
    }
    __syncthreads();

    if (is_last) {
        // bypass loads: read fresh data from coherence point, no inv needed
        float facc = 0.0f;
#pragma unroll
        for (int k = 0; k < BLOCKS / THREADS; ++k)
            facc += __hip_atomic_load(&partials[k * THREADS + threadIdx.x],
                           __ATOMIC_RELAXED, __HIP_MEMORY_SCOPE_AGENT);

#pragma unroll
        for (int off = 32; off > 0; off >>= 1)
            facc += __shfl_down(facc, off, 64);

        if (lane == 0) ws[wave] = facc;
        __syncthreads();

        if (threadIdx.x == 0) {
            out[0] = (ws[0] + ws[1] + ws[2] + ws[3]) * NEG_INV_N;
            __hip_atomic_store(&g_counter, 0,
                               __ATOMIC_RELAXED, __HIP_MEMORY_SCOPE_AGENT);
        }
    }
}

extern "C" void kernel_launch(void* const* d_in, const int* in_sizes, int n_in,
                              void* d_out, int out_size, void* d_ws, size_t ws_size,
                              hipStream_t stream) {
    const v4f* inp = (const v4f*)d_in[0];
    const v4i* tgt = (const v4i*)d_in[1];
    float*     out = (float*)d_out;
    float*     partials = (float*)d_ws;   // 8 KB scratch

    focal_fused_kernel<<<BLOCKS, THREADS, 0, stream>>>(inp, tgt, partials, out);
}

// Round 9
// 252.363 us; speedup vs baseline: 1.3681x; 1.0373x over previous
//
#include <hip/hip_runtime.h>

// Focal loss (gamma=2, w0=w1=1) mean over N=2^25: -mean(log(s)*(1-s)^2),
// s = t ? p : 1-p. Two-stage reduction (no atomics) -- R9 structure.
//
// R11 post-mortem: fusion v2 (bypass atomics) fixed the fence thrash but
// e2e 261.8 > R9's 250.8 -> launch+tail were already ~free; fused epilogue
// costs more than it saves. Fusion abandoned; back to two-kernel.
// R12 = R9 + ONE probe: all MLP-insensitivity evidence (R2/4/5/6/7) was
// collected on the CACHED path where L3 churn was the cap -- MLP couldn't
// matter there. The nt path (~3.6 TB/s read) has only run the thin
// 2-loads-in-flight loop (~2 KB/wave). Probe: explicit dbuf, 4-pair
// groups, prefetch g+1 before compute g, sched_barrier(0) pinning (R5
// proved the barrier forces liveness; R4 without it collapsed). Compiler
// emits counted vmcnt(8) itself (G7). Steady state 8-16 KB/wave in
// flight, VGPR ~80 (6 waves/SIMD -- fine).
// Readout: e2e 230-242 => nt-read was latency-limited, iterate deeper.
// 248-257 => genuine nt-read ceiling, ROOFLINE next round as-is.
// >262 => occupancy cost > MLP gain, revert exact R9 then declare.

typedef float v4f __attribute__((ext_vector_type(4)));
typedef int   v4i __attribute__((ext_vector_type(4)));

constexpr int   N_TOTAL   = 33554432;
constexpr int   N_VEC     = N_TOTAL / 4;          // 8388608 float4
constexpr int   THREADS   = 256;
constexpr int   BLOCKS    = 2048;
constexpr int   GTHREADS  = BLOCKS * THREADS;     // 524288
constexpr int   STEPS     = N_VEC / GTHREADS;     // 16
constexpr int   GSIZE     = 4;                    // vec4-pairs per group
constexpr int   GROUPS    = STEPS / GSIZE;        // 4
constexpr float NEG_INV_N = -1.0f / 33554432.0f;

__device__ __forceinline__ float term4(v4f p, v4i t) {
    float r = 0.0f;
#pragma unroll
    for (int j = 0; j < 4; ++j) {
        float s = (t[j] == 1) ? p[j] : (1.0f - p[j]);
        float q = 1.0f - s;
        r += __logf(s) * q * q;
    }
    return r;
}

__global__ __launch_bounds__(THREADS) void focal_partial_kernel(
    const v4f* __restrict__ inp,
    const v4i* __restrict__ tgt,
    float* __restrict__ partials)
{
    const int gtid = blockIdx.x * THREADS + threadIdx.x;

    v4f pbuf[2][GSIZE];
    v4i tbuf[2][GSIZE];

    // prologue: group 0's 8 nt loads
#pragma unroll
    for (int k = 0; k < GSIZE; ++k) {
        const int idx = gtid + k * GTHREADS;
        pbuf[0][k] = __builtin_nontemporal_load(&inp[idx]);
        tbuf[0][k] = __builtin_nontemporal_load(&tgt[idx]);
    }

    float acc = 0.0f;
#pragma unroll
    for (int g = 0; g < GROUPS; ++g) {           // fully unrolled: cur/nxt
        const int cur = g & 1, nxt = cur ^ 1;    // are compile-time consts
        if (g + 1 < GROUPS) {
#pragma unroll
            for (int k = 0; k < GSIZE; ++k) {
                const int idx = gtid + ((g + 1) * GSIZE + k) * GTHREADS;
                pbuf[nxt][k] = __builtin_nontemporal_load(&inp[idx]);
                tbuf[nxt][k] = __builtin_nontemporal_load(&tgt[idx]);
            }
        }
        // pin: group g+1's loads stay issued ABOVE the compute; prevents
        // the R4 collapse (loads re-sunk next to uses).
        __builtin_amdgcn_sched_barrier(0);
#pragma unroll
        for (int k = 0; k < GSIZE; ++k)
            acc += term4(pbuf[cur][k], tbuf[cur][k]);
    }

    // wave-64 shuffle reduction
#pragma unroll
    for (int off = 32; off > 0; off >>= 1)
        acc += __shfl_down(acc, off, 64);

    __shared__ float ws[THREADS / 64];
    int lane = threadIdx.x & 63;
    int wave = threadIdx.x >> 6;
    if (lane == 0) ws[wave] = acc;
    __syncthreads();

    if (threadIdx.x == 0)
        partials[blockIdx.x] = ws[0] + ws[1] + ws[2] + ws[3];
}

__global__ __launch_bounds__(THREADS) void focal_final_kernel(
    const float* __restrict__ partials,
    float* __restrict__ out)
{
    float acc = 0.0f;
#pragma unroll
    for (int k = 0; k < BLOCKS / THREADS; ++k)
        acc += partials[k * THREADS + threadIdx.x];

#pragma unroll
    for (int off = 32; off > 0; off >>= 1)
        acc += __shfl_down(acc, off, 64);

    __shared__ float ws[THREADS / 64];
    int lane = threadIdx.x & 63;
    int wave = threadIdx.x >> 6;
    if (lane == 0) ws[wave] = acc;
    __syncthreads();

    if (threadIdx.x == 0)
        out[0] = (ws[0] + ws[1] + ws[2] + ws[3]) * NEG_INV_N;
}

extern "C" void kernel_launch(void* const* d_in, const int* in_sizes, int n_in,
                              void* d_out, int out_size, void* d_ws, size_t ws_size,
                              hipStream_t stream) {
    const v4f* inp = (const v4f*)d_in[0];
    const v4i* tgt = (const v4i*)d_in[1];
    float*     out = (float*)d_out;
    float*     partials = (float*)d_ws;   // 8 KB scratch

    focal_partial_kernel<<<BLOCKS, THREADS, 0, stream>>>(inp, tgt, partials);
    focal_final_kernel<<<1, THREADS, 0, stream>>>(partials, out);
}